// Round 11
// baseline (168.992 us; speedup 1.0000x reference)
//
#include <hip/hip_runtime.h>

// LocalGLMnet fused forward, v8: wave-uniform j + SGPR weight streaming.
// History: v4 91us (VGPR=216, latency); v5 61us (68 VGPR); v6 59.5us (40 VGPR,
// occ 52% -- occupancy 2x'd, dur flat); v7 69us (NB=4 re-spilled, reverted).
// v6 replay rows show FETCH~0 (x L3-resident) at ~57us -> bottleneck is
// on-chip: ~140 load instrs/thread with load->use chains.
// v8: wave = 1 j (uniform) x 64 batches (lanes). Weights become wave-uniform
// -> readfirstlane(j) + const indices -> s_load (scalar pipe): zero LDS/VALU
// cost for weights; FMA = v_fmac v,s,v. x staged coalesced into LDS tile
// xs[r][cl][65] (transposed, odd-padded: reads are addr=C+lane, conflict-free
// single ds_read_b32 with imm offset). Edge cols zeroed in LDS (pad
// semantics); virtual rows handled by the static tap schedule.
// Per thread: 50 ds_read + ~30 ds_write + 8 global float4 + 250 v_fmac.

#define L2E 1.44269504088896340736f

__device__ __forceinline__ float fast_sigmoid(float s) {
    float e = __builtin_amdgcn_exp2f(s * (-L2E));   // exp(-s)
    return __builtin_amdgcn_rcpf(1.0f + e);         // 1/(1+exp(-s))
}

// 25-name rolling window: xw{S}{C}, slot S = row mod 5, col C = 0..4.
#define XW_DECL \
    float xw00,xw01,xw02,xw03,xw04, xw10,xw11,xw12,xw13,xw14, \
          xw20,xw21,xw22,xw23,xw24, xw30,xw31,xw32,xw33,xw34, \
          xw40,xw41,xw42,xw43,xw44;

// load x row R (5 cols) into slot S; xr base already includes (wid+2)*65+lane,
// so offsets are compile-time: R*780 + c*65 elements (imm ds offsets).
#define XLOAD_(S, R) \
    xw##S##0 = xr[(R)*780];       xw##S##1 = xr[(R)*780 + 65]; \
    xw##S##2 = xr[(R)*780 + 130]; xw##S##3 = xr[(R)*780 + 195]; \
    xw##S##4 = xr[(R)*780 + 260];
#define XLOAD(S, R) XLOAD_(S, R)

// one tap row: acc += sum_c w[I][j][DI][c] * window[slot S][c]; weights are
// wave-uniform (SGPR base wj + const index) -> s_load, v_fmac v,s,v.
#define TAP_(I, DI, S) { \
    const float* wp_ = wj + (I)*2500 + (DI)*5; \
    acc = fmaf(xw##S##4, wp_[4], fmaf(xw##S##3, wp_[3], fmaf(xw##S##2, wp_[2], \
          fmaf(xw##S##1, wp_[1], fmaf(xw##S##0, wp_[0], acc))))); }
#define TAP(I, DI, S) TAP_(I, DI, S)

// finalize output row I: center x = window slot (I%5) col 2.
#define FIN_(I, S) { \
    float itm_ = fast_sigmoid(acc); acc = 0.f; \
    fo = fmaf(xw##S##2, itm_, fo); pe = fmaf(itm_, itm_, pe); }
#define FIN(I, S) FIN_(I, S)

__global__ __launch_bounds__(256, 5)
void glm_fused(const float* __restrict__ x, const float* __restrict__ w,
               float* __restrict__ out) {
    // x tile, transposed + odd-padded: xs[(r*12 + cl)*65 + b], r<10, cl<12, b<64
    __shared__ float xs[7800];   // 31.2 KB -> 5 blocks/CU

    const int tid = threadIdx.x;
    const int qj  = blockIdx.x % 25;    // j-block: j in [qj*4, qj*4+4)
    const int bt  = blockIdx.x / 25;    // batch tile (64 batches)
    const int cb  = qj * 4 - 4;         // tile col base (16B-aligned, may be <0)
    const int bb  = bt * 64;            // batch base

    // ---- stage x tile: coalesced float4 global loads, zero out-of-range cols.
    // u -> (b, r, c4): u = b*30 + r*3 + c4 (consecutive u = consecutive 16B).
#pragma unroll
    for (int k = 0; k < 8; ++k) {
        int u = tid + (k << 8);
        if (u < 1920) {
            int b   = u / 30;
            int rc  = u - b * 30;
            int r   = rc / 3;
            int c4  = rc - r * 3;
            int col0 = cb + (c4 << 2);
            bool ok  = (unsigned)col0 <= 96u;       // float4 fully in [0,100)
            int colc = ok ? col0 : 0;
            const float4 v0 = *(const float4*)(x + (bb + b) * 1000 + r * 100 + colc);
            float vx = ok ? v0.x : 0.f, vy = ok ? v0.y : 0.f;
            float vz = ok ? v0.z : 0.f, vw = ok ? v0.w : 0.f;
            int base = (r * 12 + (c4 << 2)) * 65 + b;
            xs[base]       = vx;
            xs[base + 65]  = vy;
            xs[base + 130] = vz;
            xs[base + 195] = vw;
        }
    }
    __syncthreads();

    const int lane = tid & 63;
    const int wid  = tid >> 6;
    // j is wave-uniform; force scalarization so weight reads become s_load.
    const int j = __builtin_amdgcn_readfirstlane(qj * 4 + wid);
    const float* __restrict__ wj = w + j * 25;          // + I*2500 + DI*5 + c
    const float* __restrict__ xr = xs + (wid + 2) * 65 + lane;  // + R*780 + c*65

    XW_DECL
    float acc = 0.f, fo = 0.f, pe = 0.f;

    // prologue: rows 0,1,2 -> slots 0,1,2 (virtual rows -2,-1 are skipped taps)
    XLOAD(0, 0) XLOAD(1, 1) XLOAD(2, 2)

    // phase I: taps (DI, row I-2+DI, slot row%5), prefetch row I+3, finalize I.
    /*P0*/ XLOAD(3, 3) TAP(0,2,0) TAP(0,3,1) TAP(0,4,2)                       FIN(0, 0)
    /*P1*/ XLOAD(4, 4) TAP(1,1,0) TAP(1,2,1) TAP(1,3,2) TAP(1,4,3)            FIN(1, 1)
    /*P2*/ TAP(2,0,0) XLOAD(0, 5) TAP(2,1,1) TAP(2,2,2) TAP(2,3,3) TAP(2,4,4) FIN(2, 2)
    /*P3*/ TAP(3,0,1) XLOAD(1, 6) TAP(3,1,2) TAP(3,2,3) TAP(3,3,4) TAP(3,4,0) FIN(3, 3)
    /*P4*/ TAP(4,0,2) XLOAD(2, 7) TAP(4,1,3) TAP(4,2,4) TAP(4,3,0) TAP(4,4,1) FIN(4, 4)
    /*P5*/ TAP(5,0,3) XLOAD(3, 8) TAP(5,1,4) TAP(5,2,0) TAP(5,3,1) TAP(5,4,2) FIN(5, 0)
    /*P6*/ TAP(6,0,4) XLOAD(4, 9) TAP(6,1,0) TAP(6,2,1) TAP(6,3,2) TAP(6,4,3) FIN(6, 1)
    /*P7*/ TAP(7,0,0) TAP(7,1,1) TAP(7,2,2) TAP(7,3,3) TAP(7,4,4)             FIN(7, 2)
    /*P8*/ TAP(8,0,1) TAP(8,1,2) TAP(8,2,3) TAP(8,3,4)                        FIN(8, 3)
    /*P9*/ TAP(9,0,2) TAP(9,1,3) TAP(9,2,4)                                   FIN(9, 4)

    // out[b][ch][j], b = bb + lane
    float* ob = out + (bb + lane) * 200 + j;
    ob[0]   = fo;
    ob[100] = 0.01f * pe;
}

extern "C" void kernel_launch(void* const* d_in, const int* in_sizes, int n_in,
                              void* d_out, int out_size, void* d_ws, size_t ws_size,
                              hipStream_t stream) {
    const float* x = (const float*)d_in[0];   // (16384, 10, 100) f32
    const float* w = (const float*)d_in[1];   // (10, 100, 5, 5)  f32
    float* out = (float*)d_out;               // (16384, 2, 100)  f32
    // grid: 256 batch-tiles (64 batches) x 25 j-blocks (4 j each) = 6400 blocks
    dim3 grid(6400), block(256);
    hipLaunchKernelGGL(glm_fused, grid, block, 0, stream, x, w, out);
}